// Round 1
// baseline (9558.236 us; speedup 1.0000x reference)
//
#include <hip/hip_runtime.h>

// LSTMSimple: B=64 T=512 F=64 H=512. Persistent 64-block kernel, custom grid
// barrier, weights bf16 in LDS, fp32 cell state in registers.
// Layer1 blocks 0..31 (16 hidden units each, K = 64(x)+512(h1) = 576),
// Layer2 blocks 32..63 (16 hidden units each, K = 512(h1)+512(h2) = 1024),
// pipelined: period p computes h1[p] and h2[p-1]; 1 barrier/period.

namespace {
constexpr int Bb = 64, Tt = 512, Ff = 64, Hh = 512, Gg = 2048;
constexpr int K1 = Ff + Hh;   // 576
constexpr int K2 = Hh + Hh;   // 1024
constexpr int NB1 = 32;
constexpr int NBLK = 64;
constexpr int THREADS = 256;
constexpr int LDP1 = K1 + 8;  // LDS row pad: stride%128B != 0 -> ~2-way (free)
constexpr int LDP2 = K2 + 8;

// ws layout (bytes)
constexpr size_t WS_XBF = 0;                                // x as bf16, 4 MB
constexpr size_t WS_H1  = size_t(Bb) * Tt * Ff * 2;         // h1 dbuf (bf16)
constexpr size_t WS_H2  = WS_H1 + size_t(2) * Bb * Hh * 2;  // h2 dbuf (bf16)
constexpr size_t WS_H2F = WS_H2 + size_t(2) * Bb * Hh * 2;  // h2[T-1] fp32
constexpr size_t WS_D1  = WS_H2F + size_t(Bb) * Hh * 4;     // dense1 out fp32
constexpr size_t WS_BAR = WS_D1 + size_t(Bb) * 256 * 4;     // barrier (256B)
}  // namespace

typedef __bf16 bf16x8 __attribute__((ext_vector_type(8)));
typedef float f32x4 __attribute__((ext_vector_type(4)));

__device__ __forceinline__ float sigf(float x) { return 1.0f / (1.0f + __expf(-x)); }
__device__ __forceinline__ float tanh_(float x) {
  float e = __expf(2.0f * x);
  return 1.0f - 2.0f / (e + 1.0f);  // saturates correctly at +/-inf
}

// Sense-reversing grid barrier. All 64 blocks are co-resident (64 <= 256 CUs,
// 1 block/CU at this LDS size), so a normal launch is deadlock-free.
// __threadfence (agent-scope fence) provides the cross-XCD wb/inv (G16).
__device__ __forceinline__ void gbar(unsigned* cnt, unsigned* gen) {
  __threadfence();
  __syncthreads();
  if (threadIdx.x == 0) {
    unsigned g = __hip_atomic_load(gen, __ATOMIC_RELAXED, __HIP_MEMORY_SCOPE_AGENT);
    unsigned a = __hip_atomic_fetch_add(cnt, 1u, __ATOMIC_RELAXED, __HIP_MEMORY_SCOPE_AGENT);
    if (a == NBLK - 1) {
      __hip_atomic_store(cnt, 0u, __ATOMIC_RELAXED, __HIP_MEMORY_SCOPE_AGENT);
      __hip_atomic_store(gen, g + 1u, __ATOMIC_RELEASE, __HIP_MEMORY_SCOPE_AGENT);
    } else {
      while (__hip_atomic_load(gen, __ATOMIC_RELAXED, __HIP_MEMORY_SCOPE_AGENT) == g)
        __builtin_amdgcn_s_sleep(1);
    }
  }
  __syncthreads();
  __threadfence();
}

__global__ void lstm_prep(const float* __restrict__ x, unsigned char* __restrict__ ws) {
  const size_t tid = size_t(blockIdx.x) * blockDim.x + threadIdx.x;
  const size_t stride = size_t(gridDim.x) * blockDim.x;
  // x fp32 -> bf16
  const float4* xv = reinterpret_cast<const float4*>(x);
  ushort4* xo = reinterpret_cast<ushort4*>(ws + WS_XBF);
  const size_t nx4 = size_t(Bb) * Tt * Ff / 4;
  for (size_t i = tid; i < nx4; i += stride) {
    float4 v = xv[i];
    ushort4 o;
    o.x = __builtin_bit_cast(unsigned short, (__bf16)v.x);
    o.y = __builtin_bit_cast(unsigned short, (__bf16)v.y);
    o.z = __builtin_bit_cast(unsigned short, (__bf16)v.z);
    o.w = __builtin_bit_cast(unsigned short, (__bf16)v.w);
    xo[i] = o;
  }
  // zero h1/h2 double buffers (contiguous region)
  uint4* hz = reinterpret_cast<uint4*>(ws + WS_H1);
  const size_t nh = (size_t(4) * Bb * Hh * 2) / 16;
  uint4 z4 = {0, 0, 0, 0};
  for (size_t i = tid; i < nh; i += stride) hz[i] = z4;
  // zero barrier state
  if (tid < 64) reinterpret_cast<unsigned*>(ws + WS_BAR)[tid] = 0;
}

__global__ __launch_bounds__(THREADS, 1) void lstm_main(
    const float* __restrict__ Wi1, const float* __restrict__ Wh1, const float* __restrict__ b1,
    const float* __restrict__ Wi2, const float* __restrict__ Wh2, const float* __restrict__ b2,
    const float* __restrict__ Wd1, const float* __restrict__ bd1,
    const float* __restrict__ Wd2, const float* __restrict__ bd2,
    unsigned char* __restrict__ ws, float* __restrict__ out) {
  extern __shared__ __bf16 Wlds[];  // [64 cols][LDP] , col = gate*16 + j
  const int tid = threadIdx.x;
  const int bid = blockIdx.x;
  const bool isL2 = (bid >= NB1);
  const int hblk = (isL2 ? bid - NB1 : bid) * 16;

  const __bf16* xbf = reinterpret_cast<const __bf16*>(ws + WS_XBF);
  __bf16* h1b0 = reinterpret_cast<__bf16*>(ws + WS_H1);
  __bf16* h1b1 = h1b0 + Bb * Hh;
  __bf16* h2b0 = reinterpret_cast<__bf16*>(ws + WS_H2);
  __bf16* h2b1 = h2b0 + Bb * Hh;
  float* h2f = reinterpret_cast<float*>(ws + WS_H2F);
  float* d1 = reinterpret_cast<float*>(ws + WS_D1);
  unsigned* bar = reinterpret_cast<unsigned*>(ws + WS_BAR);

  // ---- stage weight slice into LDS (fp32 -> bf16), [c][k] k-major ----
  if (!isL2) {
    for (int idx = tid; idx < 64 * K1; idx += THREADS) {
      int k = idx >> 6, c = idx & 63;
      int gcol = (c >> 4) * Hh + hblk + (c & 15);
      float v = (k < Ff) ? Wi1[k * Gg + gcol] : Wh1[(k - Ff) * Gg + gcol];
      Wlds[c * LDP1 + k] = (__bf16)v;
    }
  } else {
    for (int idx = tid; idx < 64 * K2; idx += THREADS) {
      int k = idx >> 6, c = idx & 63;
      int gcol = (c >> 4) * Hh + hblk + (c & 15);
      float v = (k < Hh) ? Wi2[k * Gg + gcol] : Wh2[(k - Hh) * Gg + gcol];
      Wlds[c * LDP2 + k] = (__bf16)v;
    }
  }
  __syncthreads();

  const int w = tid >> 6;          // wave 0..3 -> batch rows [16w,16w+16)
  const int l = tid & 63;
  const int l15 = l & 15;
  const int lg = l >> 4;
  const int arow = w * 16 + l15;   // batch row this lane loads for A-frags
  const int crow0 = w * 16 + lg * 4;  // first batch row in acc regs (C layout)
  const int jcol = hblk + l15;     // global hidden column for this lane's acc

  const float* bsrc = isL2 ? b2 : b1;
  const float bi_ = bsrc[0 * Hh + jcol], bf_ = bsrc[1 * Hh + jcol],
              bg_ = bsrc[2 * Hh + jcol], bo_ = bsrc[3 * Hh + jcol];
  float cst[4] = {0.f, 0.f, 0.f, 0.f};  // fp32 cell state, persistent

  for (int p = 0; p <= Tt; ++p) {
    if (!isL2) {
      if (p < Tt) {
        const int t = p;
        const __bf16* hprev = ((t & 1) == 0) ? h1b1 : h1b0;
        __bf16* hout = ((t & 1) == 0) ? h1b0 : h1b1;
        bf16x8 a[18];
        const __bf16* xr = xbf + (size_t(arow) * Tt + t) * Ff + lg * 8;
        a[0] = *reinterpret_cast<const bf16x8*>(xr);
        a[1] = *reinterpret_cast<const bf16x8*>(xr + 32);
        const __bf16* hr = hprev + arow * Hh + lg * 8;
#pragma unroll
        for (int ks = 2; ks < 18; ++ks)
          a[ks] = *reinterpret_cast<const bf16x8*>(hr + (ks - 2) * 32);
        f32x4 acc[4] = {};
#pragma unroll
        for (int ks = 0; ks < 18; ++ks) {
#pragma unroll
          for (int f = 0; f < 4; ++f) {
            bf16x8 bw = *reinterpret_cast<const bf16x8*>(
                &Wlds[(f * 16 + l15) * LDP1 + ks * 32 + lg * 8]);
            acc[f] = __builtin_amdgcn_mfma_f32_16x16x32_bf16(a[ks], bw, acc[f], 0, 0, 0);
          }
        }
#pragma unroll
        for (int r = 0; r < 4; ++r) {
          float ig = sigf(acc[0][r] + bi_);
          float fg = sigf(acc[1][r] + bf_);
          float gg = tanh_(acc[2][r] + bg_);
          float og = sigf(acc[3][r] + bo_);
          cst[r] = fg * cst[r] + ig * gg;
          float hv = og * tanh_(cst[r]);
          hout[(crow0 + r) * Hh + jcol] = (__bf16)hv;
        }
      }
    } else {
      if (p >= 1) {
        const int t2 = p - 1;
        const __bf16* h1cur = ((t2 & 1) == 0) ? h1b0 : h1b1;   // h1[t2]
        const __bf16* h2prev = ((t2 & 1) == 0) ? h2b1 : h2b0;  // h2[t2-1]
        __bf16* hout = ((t2 & 1) == 0) ? h2b0 : h2b1;
        bf16x8 a[32];
        const __bf16* h1r = h1cur + arow * Hh + lg * 8;
        const __bf16* h2r = h2prev + arow * Hh + lg * 8;
#pragma unroll
        for (int ks = 0; ks < 16; ++ks)
          a[ks] = *reinterpret_cast<const bf16x8*>(h1r + ks * 32);
#pragma unroll
        for (int ks = 0; ks < 16; ++ks)
          a[16 + ks] = *reinterpret_cast<const bf16x8*>(h2r + ks * 32);
        f32x4 acc[4] = {};
#pragma unroll
        for (int ks = 0; ks < 32; ++ks) {
#pragma unroll
          for (int f = 0; f < 4; ++f) {
            bf16x8 bw = *reinterpret_cast<const bf16x8*>(
                &Wlds[(f * 16 + l15) * LDP2 + ks * 32 + lg * 8]);
            acc[f] = __builtin_amdgcn_mfma_f32_16x16x32_bf16(a[ks], bw, acc[f], 0, 0, 0);
          }
        }
#pragma unroll
        for (int r = 0; r < 4; ++r) {
          float ig = sigf(acc[0][r] + bi_);
          float fg = sigf(acc[1][r] + bf_);
          float gg = tanh_(acc[2][r] + bg_);
          float og = sigf(acc[3][r] + bo_);
          cst[r] = fg * cst[r] + ig * gg;
          float hv = og * tanh_(cst[r]);
          hout[(crow0 + r) * Hh + jcol] = (__bf16)hv;
          if (t2 == Tt - 1) h2f[(crow0 + r) * Hh + jcol] = hv;
        }
      }
    }
    gbar(bar, bar + 32);
  }

  // ---- dense head: relu(h2 @ Wd1 + bd1) -> relu(@ Wd2 + bd2) ----
  if (bid < 32) {
    for (int idx = tid; idx < 512; idx += THREADS) {
      int row = idx >> 3;
      int cc = bid * 8 + (idx & 7);
      float s = bd1[cc];
#pragma unroll 8
      for (int k = 0; k < Hh; ++k) s += h2f[row * Hh + k] * Wd1[k * 256 + cc];
      d1[row * 256 + cc] = fmaxf(s, 0.0f);
    }
  }
  gbar(bar, bar + 32);
  if (bid == 0 && tid < Bb) {
    float s = bd2[0];
#pragma unroll 8
    for (int k = 0; k < 256; ++k) s += d1[tid * 256 + k] * Wd2[k];
    out[tid] = fmaxf(s, 0.0f);
  }
}

extern "C" void kernel_launch(void* const* d_in, const int* in_sizes, int n_in,
                              void* d_out, int out_size, void* d_ws, size_t ws_size,
                              hipStream_t stream) {
  const float* x   = (const float*)d_in[0];
  // d_in[1] = training (ignored)
  const float* Wi1 = (const float*)d_in[2];
  const float* Wh1 = (const float*)d_in[3];
  const float* b1  = (const float*)d_in[4];
  const float* Wi2 = (const float*)d_in[5];
  const float* Wh2 = (const float*)d_in[6];
  const float* b2  = (const float*)d_in[7];
  const float* Wd1 = (const float*)d_in[8];
  const float* bd1 = (const float*)d_in[9];
  const float* Wd2 = (const float*)d_in[10];
  const float* bd2 = (const float*)d_in[11];
  float* out = (float*)d_out;
  unsigned char* ws = (unsigned char*)d_ws;

  hipFuncSetAttribute(reinterpret_cast<const void*>(lstm_main),
                      hipFuncAttributeMaxDynamicSharedMemorySize, 64 * LDP2 * 2);
  lstm_prep<<<1024, 256, 0, stream>>>(x, ws);
  lstm_main<<<NBLK, THREADS, 64 * LDP2 * 2, stream>>>(Wi1, Wh1, b1, Wi2, Wh2, b2,
                                                      Wd1, bd1, Wd2, bd2, ws, out);
}

// Round 3
// 4910.900 us; speedup vs baseline: 1.9463x; 1.9463x over previous
//
#include <hip/hip_runtime.h>

// LSTMSimple: B=64 T=512 F=64 H=512. Persistent 64-block kernel.
// Round 2: fence-free barrier. Shared h-state moves through IF (L3) via
// explicit sc0 sc1 loads/stores (coherent across XCDs, no L2 invalidation).
// Barrier = per-block monotonic period slots, wave0 polls 64 slots with one
// coalesced coherent load. No atomics, no __threadfence.

namespace {
constexpr int Bb = 64, Tt = 512, Ff = 64, Hh = 512, Gg = 2048;
constexpr int K1 = Ff + Hh;   // 576
constexpr int K2 = Hh + Hh;   // 1024
constexpr int NB1 = 32;
constexpr int NBLK = 64;
constexpr int THREADS = 256;
constexpr int LDP1 = K1 + 8;  // bf16 elems; row stride 1168B
constexpr int LDP2 = K2 + 8;  // row stride 2064B

// ws layout (bytes)
constexpr size_t WS_XBF = 0;                                // x as bf16, 4 MB
constexpr size_t WS_H1  = size_t(Bb) * Tt * Ff * 2;         // h1 dbuf (bf16)
constexpr size_t WS_H2  = WS_H1 + size_t(2) * Bb * Hh * 2;  // h2 dbuf (bf16)
constexpr size_t WS_H2F = WS_H2 + size_t(2) * Bb * Hh * 2;  // h2[T-1] fp32
constexpr size_t WS_D1  = WS_H2F + size_t(Bb) * Hh * 4;     // dense1 out fp32
constexpr size_t WS_BAR = WS_D1 + size_t(Bb) * 256 * 4;     // 64 slot dwords
}  // namespace

typedef __bf16 bf16x8 __attribute__((ext_vector_type(8)));
typedef float f32x4 __attribute__((ext_vector_type(4)));

__device__ __forceinline__ float sigf(float x) { return 1.0f / (1.0f + __expf(-x)); }
__device__ __forceinline__ float tanh_(float x) {
  float e = __expf(2.0f * x);
  return 1.0f - 2.0f / (e + 1.0f);
}

// ---- coherent (IF-level, cross-XCD) memory ops: bypass L1+L2 ----
__device__ __forceinline__ bf16x8 ldg16c(const __bf16* p) {
  bf16x8 r;
  asm volatile("global_load_dwordx4 %0, %1, off sc0 sc1" : "=v"(r) : "v"(p));
  return r;
}
__device__ __forceinline__ f32x4 ldg16fc(const float* p) {
  f32x4 r;
  asm volatile("global_load_dwordx4 %0, %1, off sc0 sc1" : "=v"(r) : "v"(p));
  return r;
}
__device__ __forceinline__ void stg2c(__bf16* p, unsigned v) {
  asm volatile("global_store_short %0, %1, off sc0 sc1" ::"v"(p), "v"(v) : "memory");
}
__device__ __forceinline__ void stg4c(float* p, float v) {
  asm volatile("global_store_dword %0, %1, off sc0 sc1" ::"v"(p), "v"(v) : "memory");
}
__device__ __forceinline__ void stg4cu(unsigned* p, unsigned v) {
  asm volatile("global_store_dword %0, %1, off sc0 sc1" ::"v"(p), "v"(v) : "memory");
}
__device__ __forceinline__ unsigned ldg4cu(const unsigned* p) {
  unsigned r;
  asm volatile("global_load_dword %0, %1, off sc0 sc1\n\ts_waitcnt vmcnt(0)"
               : "=v"(r) : "v"(p) : "memory");
  return r;
}
__device__ __forceinline__ void vm_drain() {
  asm volatile("s_waitcnt vmcnt(0)" ::: "memory");
  __builtin_amdgcn_sched_barrier(0);
}

// Per-block monotonic slot barrier. slots[b] = last period completed by
// block b (written sc1, polled sc1). No fences, no atomics: data stores are
// write-through (sc0 sc1) and drained (vmcnt0) before the slot store, so
// slot>=target at IF implies the data is at IF; readers bypass stale caches.
__device__ __forceinline__ void slot_barrier(unsigned* slots, int bid, int tid,
                                             unsigned target) {
  asm volatile("s_waitcnt vmcnt(0)" ::: "memory");  // drain this wave's stores
  __syncthreads();                                  // all waves drained
  if (tid == 0) stg4cu(&slots[bid], target);
  if (tid < 64) {
    for (;;) {
      unsigned v = ldg4cu(&slots[tid]);
      if (__all((int)(v >= target))) break;
      __builtin_amdgcn_s_sleep(1);
    }
  }
  __syncthreads();
}

__global__ void lstm_prep(const float* __restrict__ x, unsigned char* __restrict__ ws) {
  const size_t tid = size_t(blockIdx.x) * blockDim.x + threadIdx.x;
  const size_t stride = size_t(gridDim.x) * blockDim.x;
  const float4* xv = reinterpret_cast<const float4*>(x);
  ushort4* xo = reinterpret_cast<ushort4*>(ws + WS_XBF);
  const size_t nx4 = size_t(Bb) * Tt * Ff / 4;
  for (size_t i = tid; i < nx4; i += stride) {
    float4 v = xv[i];
    ushort4 o;
    o.x = __builtin_bit_cast(unsigned short, (__bf16)v.x);
    o.y = __builtin_bit_cast(unsigned short, (__bf16)v.y);
    o.z = __builtin_bit_cast(unsigned short, (__bf16)v.z);
    o.w = __builtin_bit_cast(unsigned short, (__bf16)v.w);
    xo[i] = o;
  }
  // zero h1/h2 double buffers (reach IF via kernel-end writeback)
  uint4* hz = reinterpret_cast<uint4*>(ws + WS_H1);
  const size_t nh = (size_t(4) * Bb * Hh * 2) / 16;
  uint4 z4 = {0, 0, 0, 0};
  for (size_t i = tid; i < nh; i += stride) hz[i] = z4;
  if (tid < 64) reinterpret_cast<unsigned*>(ws + WS_BAR)[tid] = 0;
}

__global__ __launch_bounds__(THREADS, 1) void lstm_main(
    const float* __restrict__ Wi1, const float* __restrict__ Wh1, const float* __restrict__ b1,
    const float* __restrict__ Wi2, const float* __restrict__ Wh2, const float* __restrict__ b2,
    const float* __restrict__ Wd1, const float* __restrict__ bd1,
    const float* __restrict__ Wd2, const float* __restrict__ bd2,
    unsigned char* __restrict__ ws, float* __restrict__ out) {
  extern __shared__ __bf16 Wlds[];  // [64 cols][LDP], col = gate*16 + j
  const int tid = threadIdx.x;
  const int bid = blockIdx.x;
  const bool isL2 = (bid >= NB1);
  const int hblk = (isL2 ? bid - NB1 : bid) * 16;

  const __bf16* xbf = reinterpret_cast<const __bf16*>(ws + WS_XBF);
  __bf16* h1b0 = reinterpret_cast<__bf16*>(ws + WS_H1);
  __bf16* h1b1 = h1b0 + Bb * Hh;
  __bf16* h2b0 = reinterpret_cast<__bf16*>(ws + WS_H2);
  __bf16* h2b1 = h2b0 + Bb * Hh;
  float* h2f = reinterpret_cast<float*>(ws + WS_H2F);
  float* d1 = reinterpret_cast<float*>(ws + WS_D1);
  unsigned* slots = reinterpret_cast<unsigned*>(ws + WS_BAR);

  // ---- stage weight slice into LDS (fp32 -> bf16), [c][k] k-major ----
  if (!isL2) {
    for (int idx = tid; idx < 64 * K1; idx += THREADS) {
      int k = idx >> 6, c = idx & 63;
      int gcol = (c >> 4) * Hh + hblk + (c & 15);
      float v = (k < Ff) ? Wi1[k * Gg + gcol] : Wh1[(k - Ff) * Gg + gcol];
      Wlds[c * LDP1 + k] = (__bf16)v;
    }
  } else {
    for (int idx = tid; idx < 64 * K2; idx += THREADS) {
      int k = idx >> 6, c = idx & 63;
      int gcol = (c >> 4) * Hh + hblk + (c & 15);
      float v = (k < Hh) ? Wi2[k * Gg + gcol] : Wh2[(k - Hh) * Gg + gcol];
      Wlds[c * LDP2 + k] = (__bf16)v;
    }
  }
  __syncthreads();

  const int w = tid >> 6;
  const int l = tid & 63;
  const int l15 = l & 15;
  const int lg = l >> 4;
  const int arow = w * 16 + l15;      // batch row for A-frag loads
  const int crow0 = w * 16 + lg * 4;  // first batch row in acc regs
  const int jcol = hblk + l15;        // hidden column for this lane's acc

  const float* bsrc = isL2 ? b2 : b1;
  const float bi_ = bsrc[0 * Hh + jcol], bf_ = bsrc[1 * Hh + jcol],
              bg_ = bsrc[2 * Hh + jcol], bo_ = bsrc[3 * Hh + jcol];
  float cst[4] = {0.f, 0.f, 0.f, 0.f};

  for (int p = 0; p <= Tt; ++p) {
    if (!isL2) {
      if (p < Tt) {
        const int t = p;
        const __bf16* hprev = ((t & 1) == 0) ? h1b1 : h1b0;
        __bf16* hout = ((t & 1) == 0) ? h1b0 : h1b1;
        bf16x8 a[18];
        const __bf16* xr = xbf + (size_t(arow) * Tt + t) * Ff + lg * 8;
        a[0] = *reinterpret_cast<const bf16x8*>(xr);         // x: plain cached
        a[1] = *reinterpret_cast<const bf16x8*>(xr + 32);
        const __bf16* hr = hprev + arow * Hh + lg * 8;
#pragma unroll
        for (int ks = 2; ks < 18; ++ks) a[ks] = ldg16c(hr + (ks - 2) * 32);
        vm_drain();
        f32x4 acc[4] = {};
#pragma unroll
        for (int ks = 0; ks < 18; ++ks) {
#pragma unroll
          for (int f = 0; f < 4; ++f) {
            bf16x8 bw = *reinterpret_cast<const bf16x8*>(
                &Wlds[(f * 16 + l15) * LDP1 + ks * 32 + lg * 8]);
            acc[f] = __builtin_amdgcn_mfma_f32_16x16x32_bf16(a[ks], bw, acc[f], 0, 0, 0);
          }
        }
#pragma unroll
        for (int r = 0; r < 4; ++r) {
          float ig = sigf(acc[0][r] + bi_);
          float fg = sigf(acc[1][r] + bf_);
          float gg = tanh_(acc[2][r] + bg_);
          float og = sigf(acc[3][r] + bo_);
          cst[r] = fg * cst[r] + ig * gg;
          float hv = og * tanh_(cst[r]);
          stg2c(hout + (crow0 + r) * Hh + jcol,
                (unsigned)__builtin_bit_cast(unsigned short, (__bf16)hv));
        }
      }
    } else {
      if (p >= 1) {
        const int t2 = p - 1;
        const __bf16* h1cur = ((t2 & 1) == 0) ? h1b0 : h1b1;
        const __bf16* h2prev = ((t2 & 1) == 0) ? h2b1 : h2b0;
        __bf16* hout = ((t2 & 1) == 0) ? h2b0 : h2b1;
        bf16x8 a[32];
        const __bf16* h1r = h1cur + arow * Hh + lg * 8;
        const __bf16* h2r = h2prev + arow * Hh + lg * 8;
#pragma unroll
        for (int ks = 0; ks < 16; ++ks) a[ks] = ldg16c(h1r + ks * 32);
#pragma unroll
        for (int ks = 0; ks < 16; ++ks) a[16 + ks] = ldg16c(h2r + ks * 32);
        vm_drain();
        f32x4 acc[4] = {};
#pragma unroll
        for (int ks = 0; ks < 32; ++ks) {
#pragma unroll
          for (int f = 0; f < 4; ++f) {
            bf16x8 bw = *reinterpret_cast<const bf16x8*>(
                &Wlds[(f * 16 + l15) * LDP2 + ks * 32 + lg * 8]);
            acc[f] = __builtin_amdgcn_mfma_f32_16x16x32_bf16(a[ks], bw, acc[f], 0, 0, 0);
          }
        }
#pragma unroll
        for (int r = 0; r < 4; ++r) {
          float ig = sigf(acc[0][r] + bi_);
          float fg = sigf(acc[1][r] + bf_);
          float gg = tanh_(acc[2][r] + bg_);
          float og = sigf(acc[3][r] + bo_);
          cst[r] = fg * cst[r] + ig * gg;
          float hv = og * tanh_(cst[r]);
          stg2c(hout + (crow0 + r) * Hh + jcol,
                (unsigned)__builtin_bit_cast(unsigned short, (__bf16)hv));
          if (t2 == Tt - 1) stg4c(&h2f[(crow0 + r) * Hh + jcol], hv);
        }
      }
    }
    slot_barrier(slots, bid, tid, (unsigned)(p + 1));
  }

  // ---- dense head: relu(h2 @ Wd1 + bd1) -> relu(@ Wd2 + bd2) ----
  f32x4* sh4 = reinterpret_cast<f32x4*>(Wlds);  // reuse weight LDS
  if (bid < 32) {
    // stage h2f (64x512 f32 = 128 KB) into LDS via coherent loads
    for (int it = 0; it < 4; ++it) {
      f32x4 tmp[8];
#pragma unroll
      for (int j = 0; j < 8; ++j)
        tmp[j] = ldg16fc(h2f + (size_t(it) * 2048 + j * 256 + tid) * 4);
      vm_drain();
#pragma unroll
      for (int j = 0; j < 8; ++j) sh4[size_t(it) * 2048 + j * 256 + tid] = tmp[j];
    }
    __syncthreads();
    for (int idx = tid; idx < 512; idx += THREADS) {
      int row = idx >> 3;
      int cc = bid * 8 + (idx & 7);
      float s = bd1[cc];
      const f32x4* rowp = sh4 + row * 128;
#pragma unroll 4
      for (int k4 = 0; k4 < 128; ++k4) {
        f32x4 h4 = rowp[k4];
        const float* wd = Wd1 + (k4 * 4) * 256 + cc;
        s += h4[0] * wd[0] + h4[1] * wd[256] + h4[2] * wd[512] + h4[3] * wd[768];
      }
      stg4c(&d1[row * 256 + cc], fmaxf(s, 0.0f));
    }
  }
  // final sync: everyone reports, only block 0 needs to wait
  asm volatile("s_waitcnt vmcnt(0)" ::: "memory");
  __syncthreads();
  if (tid == 0) stg4cu(&slots[bid], (unsigned)(Tt + 2));
  if (bid == 0) {
    if (tid < 64) {
      for (;;) {
        unsigned v = ldg4cu(&slots[tid]);
        if (__all((int)(v >= (unsigned)(Tt + 2)))) break;
        __builtin_amdgcn_s_sleep(1);
      }
    }
    __syncthreads();
    // stage d1 (64x256 f32 = 64 KB) into LDS
    for (int it = 0; it < 2; ++it) {
      f32x4 tmp[8];
#pragma unroll
      for (int j = 0; j < 8; ++j)
        tmp[j] = ldg16fc(d1 + (size_t(it) * 2048 + j * 256 + tid) * 4);
      vm_drain();
#pragma unroll
      for (int j = 0; j < 8; ++j) sh4[size_t(it) * 2048 + j * 256 + tid] = tmp[j];
    }
    __syncthreads();
    if (tid < Bb) {
      float s = bd2[0];
      const f32x4* rowp = sh4 + tid * 64;
#pragma unroll 4
      for (int k4 = 0; k4 < 64; ++k4) {
        f32x4 v = rowp[k4];
        s += v[0] * Wd2[k4 * 4] + v[1] * Wd2[k4 * 4 + 1] + v[2] * Wd2[k4 * 4 + 2] +
             v[3] * Wd2[k4 * 4 + 3];
      }
      out[tid] = fmaxf(s, 0.0f);
    }
  }
}

extern "C" void kernel_launch(void* const* d_in, const int* in_sizes, int n_in,
                              void* d_out, int out_size, void* d_ws, size_t ws_size,
                              hipStream_t stream) {
  const float* x   = (const float*)d_in[0];
  const float* Wi1 = (const float*)d_in[2];
  const float* Wh1 = (const float*)d_in[3];
  const float* b1  = (const float*)d_in[4];
  const float* Wi2 = (const float*)d_in[5];
  const float* Wh2 = (const float*)d_in[6];
  const float* b2  = (const float*)d_in[7];
  const float* Wd1 = (const float*)d_in[8];
  const float* bd1 = (const float*)d_in[9];
  const float* Wd2 = (const float*)d_in[10];
  const float* bd2 = (const float*)d_in[11];
  float* out = (float*)d_out;
  unsigned char* ws = (unsigned char*)d_ws;

  hipFuncSetAttribute(reinterpret_cast<const void*>(lstm_main),
                      hipFuncAttributeMaxDynamicSharedMemorySize, 64 * LDP2 * 2);
  lstm_prep<<<1024, 256, 0, stream>>>(x, ws);
  lstm_main<<<NBLK, THREADS, 64 * LDP2 * 2, stream>>>(Wi1, Wh1, b1, Wi2, Wh2, b2,
                                                      Wd1, bd1, Wd2, bd2, ws, out);
}

// Round 4
// 3628.249 us; speedup vs baseline: 2.6344x; 1.3535x over previous
//
#include <hip/hip_runtime.h>

// LSTMSimple: B=64 T=512 F=64 H=512. Persistent 64-block kernel, round 4:
// - L1 (blocks 0..31) and L2 (blocks 32..63) decoupled: per-group epoch slots,
//   h1 in an 8-deep ring so L1 runs ahead of L2 (ring guard: l2 >= t-7).
// - L2 prefetches h1[t+1] fragments into registers (L1 is ahead), so its
//   critical path is h2-only; h2 load latency hidden under h1 k-steps via
//   vmcnt(16) split.
// - MFMA operands swapped (W as A, h as B): lane holds 4 consecutive hidden
//   cols for one batch row -> h-store is one packed dwordx2 per thread.

namespace {
constexpr int Bb = 64, Tt = 512, Ff = 64, Hh = 512, Gg = 2048;
constexpr int K1 = Ff + Hh;   // 576
constexpr int K2 = Hh + Hh;   // 1024
constexpr int NB1 = 32;
constexpr int THREADS = 256;
constexpr int LDP1 = K1 + 8;
constexpr int LDP2 = K2 + 8;
constexpr int H1SLOT = Bb * Hh;  // elems per ring slot (64 KB bf16)
constexpr int RING = 8;

// ws layout (bytes)
constexpr size_t WS_XBF  = 0;                                  // x bf16, 4 MB
constexpr size_t WS_H1R  = size_t(Bb) * Tt * Ff * 2;           // h1 ring 512 KB
constexpr size_t WS_H2   = WS_H1R + size_t(RING) * H1SLOT * 2; // h2 dbuf 128 KB
constexpr size_t WS_H2F  = WS_H2 + size_t(2) * H1SLOT * 2;     // h2[T-1] f32
constexpr size_t WS_D1   = WS_H2F + size_t(Bb) * Hh * 4;       // dense1 f32
constexpr size_t WS_SLOT = WS_D1 + size_t(Bb) * 256 * 4;       // 64 dwords
}  // namespace

typedef __bf16 bf16x8 __attribute__((ext_vector_type(8)));
typedef float f32x4 __attribute__((ext_vector_type(4)));

__device__ __forceinline__ float sigf(float x) { return 1.0f / (1.0f + __expf(-x)); }
__device__ __forceinline__ float tanh_(float x) {
  float e = __expf(2.0f * x);
  return 1.0f - 2.0f / (e + 1.0f);
}

// ---- coherent (cross-XCD) ops: bypass L1+L2 ----
__device__ __forceinline__ bf16x8 ldg16c(const __bf16* p) {
  bf16x8 r;
  asm volatile("global_load_dwordx4 %0, %1, off sc0 sc1" : "=v"(r) : "v"(p));
  return r;
}
__device__ __forceinline__ f32x4 ldg16fc(const float* p) {
  f32x4 r;
  asm volatile("global_load_dwordx4 %0, %1, off sc0 sc1" : "=v"(r) : "v"(p));
  return r;
}
__device__ __forceinline__ void stg8c(__bf16* p, unsigned lo, unsigned hi) {
  unsigned long long d = (unsigned long long)lo | ((unsigned long long)hi << 32);
  asm volatile("global_store_dwordx2 %0, %1, off sc0 sc1" ::"v"(p), "v"(d) : "memory");
}
__device__ __forceinline__ void stg16fc(float* p, f32x4 v) {
  asm volatile("global_store_dwordx4 %0, %1, off sc0 sc1" ::"v"(p), "v"(v) : "memory");
}
__device__ __forceinline__ void stg4c(float* p, float v) {
  asm volatile("global_store_dword %0, %1, off sc0 sc1" ::"v"(p), "v"(v) : "memory");
}
__device__ __forceinline__ void stg4cu(unsigned* p, unsigned v) {
  asm volatile("global_store_dword %0, %1, off sc0 sc1" ::"v"(p), "v"(v) : "memory");
}
__device__ __forceinline__ unsigned ldg4cu(const unsigned* p) {
  unsigned r;
  asm volatile("global_load_dword %0, %1, off sc0 sc1\n\ts_waitcnt vmcnt(0)"
               : "=v"(r) : "v"(p) : "memory");
  return r;
}
__device__ __forceinline__ void vm_drain() {
  asm volatile("s_waitcnt vmcnt(0)" ::: "memory");
  __builtin_amdgcn_sched_barrier(0);
}
__device__ __forceinline__ void vm_wait16() {
  asm volatile("s_waitcnt vmcnt(16)" ::: "memory");
  __builtin_amdgcn_sched_barrier(0);
}

// Epoch poll: lane l (0..63) watches slots[l]; lanes<32 = L1 group, >=32 = L2.
// `seen` caches last-read values; slots are monotonic so a cached pass is safe.
__device__ __forceinline__ void poll2(const unsigned* slots, int l, unsigned tlo,
                                      unsigned thi, unsigned& seen) {
  const unsigned tgt = (l < 32) ? tlo : thi;
  if (__all((int)(seen >= tgt))) return;
  for (;;) {
    unsigned v = ldg4cu(slots + l);
    seen = v;
    if (__all((int)(v >= tgt))) return;
    __builtin_amdgcn_s_sleep(1);
  }
}

__global__ void lstm_prep(const float* __restrict__ x, unsigned char* __restrict__ ws) {
  const size_t tid = size_t(blockIdx.x) * blockDim.x + threadIdx.x;
  const size_t stride = size_t(gridDim.x) * blockDim.x;
  const float4* xv = reinterpret_cast<const float4*>(x);
  ushort4* xo = reinterpret_cast<ushort4*>(ws + WS_XBF);
  const size_t nx4 = size_t(Bb) * Tt * Ff / 4;
  for (size_t i = tid; i < nx4; i += stride) {
    float4 v = xv[i];
    ushort4 o;
    o.x = __builtin_bit_cast(unsigned short, (__bf16)v.x);
    o.y = __builtin_bit_cast(unsigned short, (__bf16)v.y);
    o.z = __builtin_bit_cast(unsigned short, (__bf16)v.z);
    o.w = __builtin_bit_cast(unsigned short, (__bf16)v.w);
    xo[i] = o;
  }
  // zero h1 ring + h2 dbuf (contiguous)
  uint4* hz = reinterpret_cast<uint4*>(ws + WS_H1R);
  const size_t nh = (size_t(RING) * H1SLOT * 2 + size_t(2) * H1SLOT * 2) / 16;
  uint4 z4 = {0, 0, 0, 0};
  for (size_t i = tid; i < nh; i += stride) hz[i] = z4;
  if (tid < 64) reinterpret_cast<unsigned*>(ws + WS_SLOT)[tid] = 0;
}

__global__ __launch_bounds__(THREADS, 1) void lstm_main(
    const float* __restrict__ Wi1, const float* __restrict__ Wh1, const float* __restrict__ b1,
    const float* __restrict__ Wi2, const float* __restrict__ Wh2, const float* __restrict__ b2,
    const float* __restrict__ Wd1, const float* __restrict__ bd1,
    const float* __restrict__ Wd2, const float* __restrict__ bd2,
    unsigned char* __restrict__ ws, float* __restrict__ out) {
  extern __shared__ __bf16 Wlds[];  // [64 cols][LDP], col = gate*16 + j
  const int tid = threadIdx.x;
  const int bid = blockIdx.x;
  const bool isL2 = (bid >= NB1);
  const int hblk = (isL2 ? bid - NB1 : bid) * 16;

  const __bf16* xbf = reinterpret_cast<const __bf16*>(ws + WS_XBF);
  __bf16* h1ring = reinterpret_cast<__bf16*>(ws + WS_H1R);
  __bf16* h2b0 = reinterpret_cast<__bf16*>(ws + WS_H2);
  __bf16* h2b1 = h2b0 + H1SLOT;
  float* h2f = reinterpret_cast<float*>(ws + WS_H2F);
  float* d1 = reinterpret_cast<float*>(ws + WS_D1);
  unsigned* slots = reinterpret_cast<unsigned*>(ws + WS_SLOT);

  // ---- stage weight slice into LDS (fp32 -> bf16), [c][k] k-major ----
  if (!isL2) {
    for (int idx = tid; idx < 64 * K1; idx += THREADS) {
      int k = idx >> 6, c = idx & 63;
      int gcol = (c >> 4) * Hh + hblk + (c & 15);
      float v = (k < Ff) ? Wi1[k * Gg + gcol] : Wh1[(k - Ff) * Gg + gcol];
      Wlds[c * LDP1 + k] = (__bf16)v;
    }
  } else {
    for (int idx = tid; idx < 64 * K2; idx += THREADS) {
      int k = idx >> 6, c = idx & 63;
      int gcol = (c >> 4) * Hh + hblk + (c & 15);
      float v = (k < Hh) ? Wi2[k * Gg + gcol] : Wh2[(k - Hh) * Gg + gcol];
      Wlds[c * LDP2 + k] = (__bf16)v;
    }
  }
  __syncthreads();

  const int w = tid >> 6;
  const int l = tid & 63;
  const int l15 = l & 15;
  const int lg = l >> 4;
  const int arow = w * 16 + l15;       // batch row (B-operand + store row)
  const int col0 = hblk + lg * 4;      // first of 4 consecutive hidden cols

  const float* bsrc = isL2 ? b2 : b1;
  f32x4 bi4 = *reinterpret_cast<const f32x4*>(&bsrc[0 * Hh + col0]);
  f32x4 bf4 = *reinterpret_cast<const f32x4*>(&bsrc[1 * Hh + col0]);
  f32x4 bg4 = *reinterpret_cast<const f32x4*>(&bsrc[2 * Hh + col0]);
  f32x4 bo4 = *reinterpret_cast<const f32x4*>(&bsrc[3 * Hh + col0]);
  f32x4 cst = {0.f, 0.f, 0.f, 0.f};  // cell state: 4 hidden units, 1 batch row
  unsigned seen = 0;

  if (!isL2) {
    // =================== Layer 1 ===================
    for (int t = 0; t < Tt; ++t) {
      // x frags (plain cached) — issue before poll
      const __bf16* xr = xbf + (size_t(arow) * Tt + t) * Ff + lg * 8;
      bf16x8 ax0 = *reinterpret_cast<const bf16x8*>(xr);
      bf16x8 ax1 = *reinterpret_cast<const bf16x8*>(xr + 32);
      // wait: own group at epoch t; ring guard: L2 finished t-8 (slots>=t-7)
      poll2(slots, l, (unsigned)t, (t >= 8) ? (unsigned)(t - 7) : 0u, seen);
      // issue h1[t-1] loads (ring slot (t-1)&7)
      const __bf16* hr = h1ring + size_t((t + RING - 1) & (RING - 1)) * H1SLOT +
                         size_t(arow) * Hh + lg * 8;
      bf16x8 ah[16];
#pragma unroll
      for (int ks = 0; ks < 16; ++ks) ah[ks] = ldg16c(hr + ks * 32);
      f32x4 acc[4] = {};
      // x k-steps while h loads fly
#pragma unroll
      for (int f = 0; f < 4; ++f) {
        bf16x8 w0 = *reinterpret_cast<const bf16x8*>(&Wlds[(f * 16 + l15) * LDP1 + lg * 8]);
        acc[f] = __builtin_amdgcn_mfma_f32_16x16x32_bf16(w0, ax0, acc[f], 0, 0, 0);
        bf16x8 w1 = *reinterpret_cast<const bf16x8*>(&Wlds[(f * 16 + l15) * LDP1 + 32 + lg * 8]);
        acc[f] = __builtin_amdgcn_mfma_f32_16x16x32_bf16(w1, ax1, acc[f], 0, 0, 0);
      }
      vm_drain();
#pragma unroll
      for (int ks = 0; ks < 16; ++ks) {
#pragma unroll
        for (int f = 0; f < 4; ++f) {
          bf16x8 bw = *reinterpret_cast<const bf16x8*>(
              &Wlds[(f * 16 + l15) * LDP1 + (ks + 2) * 32 + lg * 8]);
          acc[f] = __builtin_amdgcn_mfma_f32_16x16x32_bf16(bw, ah[ks], acc[f], 0, 0, 0);
        }
      }
      float hv[4];
#pragma unroll
      for (int r = 0; r < 4; ++r) {
        float ig = sigf(acc[0][r] + bi4[r]);
        float fg = sigf(acc[1][r] + bf4[r]);
        float gg = tanh_(acc[2][r] + bg4[r]);
        float og = sigf(acc[3][r] + bo4[r]);
        cst[r] = fg * cst[r] + ig * gg;
        hv[r] = og * tanh_(cst[r]);
      }
      unsigned plo = (unsigned)__builtin_bit_cast(unsigned short, (__bf16)hv[0]) |
                     ((unsigned)__builtin_bit_cast(unsigned short, (__bf16)hv[1]) << 16);
      unsigned phi = (unsigned)__builtin_bit_cast(unsigned short, (__bf16)hv[2]) |
                     ((unsigned)__builtin_bit_cast(unsigned short, (__bf16)hv[3]) << 16);
      stg8c(h1ring + size_t(t & (RING - 1)) * H1SLOT + size_t(arow) * Hh + col0, plo, phi);
      vm_drain();
      __syncthreads();
      if (tid == 0) stg4cu(&slots[bid], (unsigned)(t + 1));
    }
  } else {
    // =================== Layer 2 ===================
    // prime: wait for h1[0], load its fragments
    poll2(slots, l, 1u, 0u, seen);
    bf16x8 ah1[16];
    {
      const __bf16* h1r = h1ring + size_t(arow) * Hh + lg * 8;
#pragma unroll
      for (int ks = 0; ks < 16; ++ks) ah1[ks] = ldg16c(h1r + ks * 32);
      vm_drain();
    }
    for (int t = 0; t < Tt; ++t) {
      unsigned lo = (unsigned)((t + 2 < Tt) ? t + 2 : Tt);
      poll2(slots, l, lo, (unsigned)t, seen);
      // issue h2[t-1] loads
      const __bf16* h2r = (((t & 1) == 0) ? h2b1 : h2b0) + size_t(arow) * Hh + lg * 8;
      bf16x8 ah2[16];
#pragma unroll
      for (int ks = 0; ks < 16; ++ks) ah2[ks] = ldg16c(h2r + ks * 32);
      // h1-part k-steps (regs already loaded) hide the h2 load latency
      f32x4 acc[4] = {};
#pragma unroll
      for (int ks = 0; ks < 16; ++ks) {
#pragma unroll
        for (int f = 0; f < 4; ++f) {
          bf16x8 bw = *reinterpret_cast<const bf16x8*>(
              &Wlds[(f * 16 + l15) * LDP2 + ks * 32 + lg * 8]);
          acc[f] = __builtin_amdgcn_mfma_f32_16x16x32_bf16(bw, ah1[ks], acc[f], 0, 0, 0);
        }
      }
      // prefetch h1[t+1] (exists: poll guaranteed l1 >= t+2)
      if (t + 1 < Tt) {
        const __bf16* h1n = h1ring + size_t((t + 1) & (RING - 1)) * H1SLOT +
                            size_t(arow) * Hh + lg * 8;
#pragma unroll
        for (int ks = 0; ks < 16; ++ks) ah1[ks] = ldg16c(h1n + ks * 32);
        vm_wait16();  // oldest 16 (= ah2) retired; prefetch still in flight
      } else {
        vm_drain();
      }
#pragma unroll
      for (int ks = 0; ks < 16; ++ks) {
#pragma unroll
        for (int f = 0; f < 4; ++f) {
          bf16x8 bw = *reinterpret_cast<const bf16x8*>(
              &Wlds[(f * 16 + l15) * LDP2 + (16 + ks) * 32 + lg * 8]);
          acc[f] = __builtin_amdgcn_mfma_f32_16x16x32_bf16(bw, ah2[ks], acc[f], 0, 0, 0);
        }
      }
      float hv[4];
#pragma unroll
      for (int r = 0; r < 4; ++r) {
        float ig = sigf(acc[0][r] + bi4[r]);
        float fg = sigf(acc[1][r] + bf4[r]);
        float gg = tanh_(acc[2][r] + bg4[r]);
        float og = sigf(acc[3][r] + bo4[r]);
        cst[r] = fg * cst[r] + ig * gg;
        hv[r] = og * tanh_(cst[r]);
      }
      unsigned plo = (unsigned)__builtin_bit_cast(unsigned short, (__bf16)hv[0]) |
                     ((unsigned)__builtin_bit_cast(unsigned short, (__bf16)hv[1]) << 16);
      unsigned phi = (unsigned)__builtin_bit_cast(unsigned short, (__bf16)hv[2]) |
                     ((unsigned)__builtin_bit_cast(unsigned short, (__bf16)hv[3]) << 16);
      stg8c((((t & 1) == 0) ? h2b0 : h2b1) + size_t(arow) * Hh + col0, plo, phi);
      if (t == Tt - 1) {
        f32x4 hv4 = {hv[0], hv[1], hv[2], hv[3]};
        stg16fc(&h2f[size_t(arow) * Hh + col0], hv4);
      }
      vm_drain();
      __syncthreads();
      if (tid == 0) stg4cu(&slots[bid], (unsigned)(t + 1));
    }
    return;  // L2 blocks done
  }

  // ---- dense head (L1 blocks): relu(h2 @ Wd1 + bd1) -> relu(@ Wd2 + bd2) ----
  poll2(slots, l, 0u, (unsigned)Tt, seen);  // wait all L2 done
  f32x4* sh4 = reinterpret_cast<f32x4*>(Wlds);
  // stage h2f (64x512 f32 = 128 KB) into LDS
  for (int it = 0; it < 4; ++it) {
    f32x4 tmp[8];
#pragma unroll
    for (int j = 0; j < 8; ++j)
      tmp[j] = ldg16fc(h2f + (size_t(it) * 2048 + j * 256 + tid) * 4);
    vm_drain();
#pragma unroll
    for (int j = 0; j < 8; ++j) sh4[size_t(it) * 2048 + j * 256 + tid] = tmp[j];
  }
  __syncthreads();
  for (int idx = tid; idx < 512; idx += THREADS) {
    int row = idx >> 3;
    int cc = bid * 8 + (idx & 7);
    float s = bd1[cc];
    const f32x4* rowp = sh4 + row * 128;
#pragma unroll 4
    for (int k4 = 0; k4 < 128; ++k4) {
      f32x4 h4 = rowp[k4];
      const float* wd = Wd1 + (k4 * 4) * 256 + cc;
      s += h4[0] * wd[0] + h4[1] * wd[256] + h4[2] * wd[512] + h4[3] * wd[768];
    }
    stg4c(&d1[row * 256 + cc], fmaxf(s, 0.0f));
  }
  vm_drain();
  __syncthreads();
  if (tid == 0) stg4cu(&slots[bid], (unsigned)(Tt + 1));
  if (bid == 0) {
    poll2(slots, l, (unsigned)(Tt + 1), 0u, seen);  // all dense1 done
    __syncthreads();
    for (int it = 0; it < 2; ++it) {
      f32x4 tmp[8];
#pragma unroll
      for (int j = 0; j < 8; ++j)
        tmp[j] = ldg16fc(d1 + (size_t(it) * 2048 + j * 256 + tid) * 4);
      vm_drain();
#pragma unroll
      for (int j = 0; j < 8; ++j) sh4[size_t(it) * 2048 + j * 256 + tid] = tmp[j];
    }
    __syncthreads();
    if (tid < Bb) {
      float s = bd2[0];
      const f32x4* rowp = sh4 + tid * 64;
#pragma unroll 4
      for (int k4 = 0; k4 < 64; ++k4) {
        f32x4 v = rowp[k4];
        s += v[0] * Wd2[k4 * 4] + v[1] * Wd2[k4 * 4 + 1] + v[2] * Wd2[k4 * 4 + 2] +
             v[3] * Wd2[k4 * 4 + 3];
      }
      out[tid] = fmaxf(s, 0.0f);
    }
  }
}

extern "C" void kernel_launch(void* const* d_in, const int* in_sizes, int n_in,
                              void* d_out, int out_size, void* d_ws, size_t ws_size,
                              hipStream_t stream) {
  const float* x   = (const float*)d_in[0];
  const float* Wi1 = (const float*)d_in[2];
  const float* Wh1 = (const float*)d_in[3];
  const float* b1  = (const float*)d_in[4];
  const float* Wi2 = (const float*)d_in[5];
  const float* Wh2 = (const float*)d_in[6];
  const float* b2  = (const float*)d_in[7];
  const float* Wd1 = (const float*)d_in[8];
  const float* bd1 = (const float*)d_in[9];
  const float* Wd2 = (const float*)d_in[10];
  const float* bd2 = (const float*)d_in[11];
  float* out = (float*)d_out;
  unsigned char* ws = (unsigned char*)d_ws;

  hipFuncSetAttribute(reinterpret_cast<const void*>(lstm_main),
                      hipFuncAttributeMaxDynamicSharedMemorySize, 64 * LDP2 * 2);
  lstm_prep<<<1024, 256, 0, stream>>>(x, ws);
  lstm_main<<<64, THREADS, 64 * LDP2 * 2, stream>>>(Wi1, Wh1, b1, Wi2, Wh2, b2,
                                                    Wd1, bd1, Wd2, bd2, ws, out);
}